// Round 6
// baseline (5671.552 us; speedup 1.0000x reference)
//
#include <hip/hip_runtime.h>

// x[2048,64,2] -> MLP(2->16 relu ->16) -> 8x LSTM(H=64) -> MLP(64->32 relu ->4)
// fp32 in/out. LSTM via split-bf16 MFMA (3-term, ~fp32 accuracy).
//
// Round 6: layer-pipelined persistent LSTM, spill-safe.
//   Grid 512 = 8 layers x 64 mgroups (M=32 rows), 256-thr blocks, lb(256,2):
//   512 blocks x 4 waves = 2048 waves = 8/CU -> ALL blocks co-resident
//   (no deadlock, 2 independent blocks/CU hide each other's latency).
//   h crosses layers as packed (bf16hi | bf16lo<<16) u32 rings (depth 8, L2-hot,
//   same-XCD pairing via bx%8); consumer unpacks with v_perm. LDS panel holds
//   h only (x comes straight from global); 1 barrier/step; reg-local phase C.

#define BATCH 2048
#define TT 64
#define LDPW 72      // panel row stride in u32
#define RD 8         // ring depth (timesteps)

typedef unsigned int u32;
typedef u32 u32x4 __attribute__((ext_vector_type(4)));
typedef short bf16x8 __attribute__((ext_vector_type(8)));
typedef float f32x4 __attribute__((ext_vector_type(4)));

__device__ __forceinline__ float sigmoid_fast(float x) {
    return __builtin_amdgcn_rcpf(1.f + __expf(-x));
}
__device__ __forceinline__ float tanh_fast(float x) {
    float e = __expf(-2.f * x);
    e = fminf(e, 1e30f);
    return (1.f - e) * __builtin_amdgcn_rcpf(1.f + e);
}
// fp32 -> (bf16 hi) | (bf16 lo of exact residual) << 16
__device__ __forceinline__ u32 pack_split(float x) {
    const u32 u = __float_as_uint(x);
    const float r = x - __uint_as_float(u & 0xFFFF0000u);
    return (u >> 16) | (__float_as_uint(r) & 0xFFFF0000u);
}
__device__ __forceinline__ void split2(float x, unsigned short& hi, unsigned short& lo) {
    const u32 u = __float_as_uint(x);
    hi = (unsigned short)(u >> 16);
    const float r = x - __uint_as_float(u & 0xFFFF0000u);
    lo = (unsigned short)(__float_as_uint(r) >> 16);
}
// 8 packed u32 -> hi-frag, lo-frag (bf16x8 each) via v_perm
__device__ __forceinline__ void unpack_frag(const u32x4 a, const u32x4 b, bf16x8& hi, bf16x8& lo) {
    union { bf16x8 v; u32 w[4]; } H, L;
    H.w[0] = __builtin_amdgcn_perm(a.y, a.x, 0x05040100u);
    H.w[1] = __builtin_amdgcn_perm(a.w, a.z, 0x05040100u);
    H.w[2] = __builtin_amdgcn_perm(b.y, b.x, 0x05040100u);
    H.w[3] = __builtin_amdgcn_perm(b.w, b.z, 0x05040100u);
    L.w[0] = __builtin_amdgcn_perm(a.y, a.x, 0x07060302u);
    L.w[1] = __builtin_amdgcn_perm(a.w, a.z, 0x07060302u);
    L.w[2] = __builtin_amdgcn_perm(b.y, b.x, 0x07060302u);
    L.w[3] = __builtin_amdgcn_perm(b.w, b.z, 0x07060302u);
    hi = H.v; lo = L.v;
}

__device__ __forceinline__ int ld_acq(const int* p) {
    return __hip_atomic_load(p, __ATOMIC_ACQUIRE, __HIP_MEMORY_SCOPE_AGENT);
}
__device__ __forceinline__ int ld_rlx(const int* p) {
    return __hip_atomic_load(p, __ATOMIC_RELAXED, __HIP_MEMORY_SCOPE_AGENT);
}
__device__ __forceinline__ void st_rel(int* p, int v) {
    __hip_atomic_store(p, v, __ATOMIC_RELEASE, __HIP_MEMORY_SCOPE_AGENT);
}

// ---------------- input MLP: 2 -> 16 relu -> 16 (packed hi/lo out) ----------------
__global__ __launch_bounds__(256)
void mlp_in_kernel(const float* __restrict__ x,
                   const float* __restrict__ w1, const float* __restrict__ b1,
                   const float* __restrict__ w2, const float* __restrict__ b2,
                   u32* __restrict__ out) {
    const int gid = blockIdx.x * 256 + threadIdx.x;
    const float x0 = x[gid * 2 + 0];
    const float x1 = x[gid * 2 + 1];
    float hid[16];
#pragma unroll
    for (int j = 0; j < 16; ++j) {
        float v = fmaf(x1, w1[j * 2 + 1], fmaf(x0, w1[j * 2 + 0], b1[j]));
        hid[j] = fmaxf(0.f, v);
    }
    u32 o[16];
#pragma unroll
    for (int oo = 0; oo < 16; ++oo) {
        float acc = b2[oo];
#pragma unroll
        for (int j = 0; j < 16; ++j) acc = fmaf(hid[j], w2[oo * 16 + j], acc);
        o[oo] = pack_split(acc);
    }
    u32x4* op = (u32x4*)(out + gid * 16);
#pragma unroll
    for (int q = 0; q < 4; ++q) {
        u32x4 v = {o[q * 4 + 0], o[q * 4 + 1], o[q * 4 + 2], o[q * 4 + 3]};
        op[q] = v;
    }
}

__global__ void clear_flags_kernel(int* flags, int n) {
    for (int i = threadIdx.x; i < n; i += 256) flags[i] = 0;
}

// ---------------- one pipelined LSTM layer ----------------
// XKT: # of 32-wide k-tiles holding x (1 for I=16, 2 for I=64); h occupies tiles XKT..XKT+1.
template <int XKT, int I, bool HAS_PREV, bool HAS_NEXT>
__device__ __forceinline__ void pipe_layer(
    const u32* __restrict__ xin, int inT,    // packed input [row][inT][I]
    u32* __restrict__ ringout,               // packed out [row][RD][64]   (HAS_NEXT)
    float* __restrict__ fout,                // fp32 out [row][64][64]     (!HAS_NEXT)
    const float* __restrict__ w_ih, const float* __restrict__ w_hh,
    const float* __restrict__ b_ih, const float* __restrict__ b_hh,
    int base, u32* pw,
    const int* prod_prev, int* cons_prev, const int* cons_own, int* prod_own) {
    constexpr int KT = XKT + 2;
    constexpr int IPAD = XKT * 32;

    const int tid = threadIdx.x;
    const int wv = tid >> 6, lane = tid & 63, l16 = lane & 15, quad = lane >> 4;
    const int j = wv * 16 + l16;   // this thread's h column

    // zero panel (h(-1) = 0)
    for (int e = tid; e < 2 * 32 * LDPW; e += 256) pw[e] = 0;

    // --- weights: wave wv owns gates i,f,g,o for columns j in [16wv,16wv+16) ---
    bf16x8 bh[KT][4], bl[KT][4];
    float bias[4];
#pragma unroll
    for (int g = 0; g < 4; ++g) {
        const int n = g * 64 + wv * 16 + l16;
        bias[g] = b_ih[n] + b_hh[n];
#pragma unroll
        for (int kt = 0; kt < KT; ++kt) {
#pragma unroll
            for (int jj = 0; jj < 8; ++jj) {
                const int k = kt * 32 + quad * 8 + jj;
                float w = 0.f;
                if (k < I) w = w_ih[n * I + k];
                else if (k >= IPAD) w = w_hh[n * 64 + (k - IPAD)];
                unsigned short h_, l_;
                split2(w, h_, l_);
                bh[kt][g][jj] = (short)h_;
                bl[kt][g][jj] = (short)l_;
            }
        }
    }

    float c[2][4] = {{0.f, 0.f, 0.f, 0.f}, {0.f, 0.f, 0.f, 0.f}};
    __syncthreads();  // panel zeroed

    for (int t = 0; t < TT; ++t) {
        // ---- per-wave uniform spins (no barrier needed) ----
        if (HAS_PREV) {
            while (ld_acq(prod_prev) < t + 1) __builtin_amdgcn_s_sleep(2);
        }
        if (HAS_NEXT) {
            while (ld_rlx(cons_own) < t - (RD - 1)) __builtin_amdgcn_s_sleep(2);
        }

        // ---- x loads (global, packed) for A-frag rows l16 / l16+16 ----
        const int ts_in = HAS_PREV ? (t & (RD - 1)) : t;
        u32x4 xa[2][XKT], xb[2][XKT];
#pragma unroll
        for (int rt = 0; rt < 2; ++rt) {
#pragma unroll
            for (int xk = 0; xk < XKT; ++xk) {
                const int k0 = xk * 32 + quad * 8;
                u32x4 za = {0, 0, 0, 0}, zb = {0, 0, 0, 0};
                if (k0 < I) {
                    const u32* xrow = xin + ((size_t)(base + l16 + rt * 16) * inT + ts_in) * I;
                    za = *(const u32x4*)&xrow[k0];
                    zb = *(const u32x4*)&xrow[k0 + 4];
                }
                xa[rt][xk] = za; xb[rt][xk] = zb;
            }
        }

        // ---- phase B ----
        const u32* pp = pw + (t & 1) * (32 * LDPW);
        u32* pn = pw + ((t & 1) ^ 1) * (32 * LDPW);
        f32x4 acc[2][4];
#pragma unroll
        for (int rt = 0; rt < 2; ++rt)
#pragma unroll
            for (int g = 0; g < 4; ++g) {
                acc[rt][g][0] = bias[g]; acc[rt][g][1] = bias[g];
                acc[rt][g][2] = bias[g]; acc[rt][g][3] = bias[g];
            }
        // h part from LDS panel
#pragma unroll
        for (int rt = 0; rt < 2; ++rt) {
#pragma unroll
            for (int hk = 0; hk < 2; ++hk) {
                const int off = (l16 + rt * 16) * LDPW + hk * 32 + quad * 8;
                const u32x4 a = *(const u32x4*)&pp[off];
                const u32x4 b2 = *(const u32x4*)&pp[off + 4];
                bf16x8 fh, fl;
                unpack_frag(a, b2, fh, fl);
#pragma unroll
                for (int g = 0; g < 4; ++g) {
                    acc[rt][g] = __builtin_amdgcn_mfma_f32_16x16x32_bf16(fh, bh[XKT + hk][g], acc[rt][g], 0, 0, 0);
                    acc[rt][g] = __builtin_amdgcn_mfma_f32_16x16x32_bf16(fl, bh[XKT + hk][g], acc[rt][g], 0, 0, 0);
                    acc[rt][g] = __builtin_amdgcn_mfma_f32_16x16x32_bf16(fh, bl[XKT + hk][g], acc[rt][g], 0, 0, 0);
                }
            }
        }
        // x part from registers
#pragma unroll
        for (int rt = 0; rt < 2; ++rt) {
#pragma unroll
            for (int xk = 0; xk < XKT; ++xk) {
                bf16x8 fh, fl;
                unpack_frag(xa[rt][xk], xb[rt][xk], fh, fl);
#pragma unroll
                for (int g = 0; g < 4; ++g) {
                    acc[rt][g] = __builtin_amdgcn_mfma_f32_16x16x32_bf16(fh, bh[xk][g], acc[rt][g], 0, 0, 0);
                    acc[rt][g] = __builtin_amdgcn_mfma_f32_16x16x32_bf16(fl, bh[xk][g], acc[rt][g], 0, 0, 0);
                    acc[rt][g] = __builtin_amdgcn_mfma_f32_16x16x32_bf16(fh, bl[xk][g], acc[rt][g], 0, 0, 0);
                }
            }
        }

        // ---- phase C: reg-local; D row = quad*4+r (+16rt), col = l16 ----
#pragma unroll
        for (int rt = 0; rt < 2; ++rt) {
#pragma unroll
            for (int r = 0; r < 4; ++r) {
                const int m = rt * 16 + quad * 4 + r;
                const float iv = sigmoid_fast(acc[rt][0][r]);
                const float fv = sigmoid_fast(acc[rt][1][r]);
                const float gv = tanh_fast(acc[rt][2][r]);
                const float ov = sigmoid_fast(acc[rt][3][r]);
                c[rt][r] = fv * c[rt][r] + iv * gv;
                const float h = ov * tanh_fast(c[rt][r]);
                const u32 pk = pack_split(h);
                pn[m * LDPW + j] = pk;
                if (HAS_NEXT) {
                    ringout[((size_t)(base + m) * RD + (t & (RD - 1))) * 64 + j] = pk;
                } else {
                    fout[((size_t)(base + m) * TT + t) * 64 + j] = h;
                }
            }
        }

        if (HAS_NEXT) __threadfence();
        __syncthreads();   // one barrier/step: panel handoff + release point
        if (tid == 0) {
            if (HAS_NEXT) st_rel(prod_own, t + 1);
            if (HAS_PREV) st_rel(cons_prev, t + 1);
        }
    }
}

// ---------------- pipelined 8-layer kernel ----------------
__global__ __launch_bounds__(256, 2)
void lstm_pipe(const u32* __restrict__ buf_mlp,
               const float* __restrict__ w_ih0, const float* __restrict__ w_hh0,
               const float* __restrict__ b_ih0, const float* __restrict__ b_hh0,
               const float* __restrict__ w_ih, const float* __restrict__ w_hh,
               const float* __restrict__ b_ih, const float* __restrict__ b_hh,
               u32* __restrict__ rings, float* __restrict__ finalb,
               int* __restrict__ prod, int* __restrict__ cons) {
    __shared__ u32 pw[2 * 32 * LDPW];
    const int l = blockIdx.x >> 6;    // layer 0..7 (layer-0 blocks dispatch first)
    const int g = blockIdx.x & 63;    // mgroup; same g -> same bx%8 across layers (XCD pairing)
    const int base = g * 32;
    const size_t ringsz = (size_t)BATCH * RD * 64;

    if (l == 0) {
        pipe_layer<1, 16, false, true>(buf_mlp, TT, rings, nullptr,
                                       w_ih0, w_hh0, b_ih0, b_hh0, base, pw,
                                       nullptr, nullptr, &cons[g], &prod[g]);
    } else if (l < 7) {
        pipe_layer<2, 64, true, true>(rings + (size_t)(l - 1) * ringsz, RD,
                                      rings + (size_t)l * ringsz, nullptr,
                                      w_ih + (size_t)(l - 1) * 256 * 64, w_hh + (size_t)(l - 1) * 256 * 64,
                                      b_ih + (size_t)(l - 1) * 256, b_hh + (size_t)(l - 1) * 256,
                                      base, pw,
                                      &prod[(l - 1) * 64 + g], &cons[(l - 1) * 64 + g],
                                      &cons[l * 64 + g], &prod[l * 64 + g]);
    } else {
        pipe_layer<2, 64, true, false>(rings + (size_t)6 * ringsz, RD, nullptr, finalb,
                                       w_ih + (size_t)6 * 256 * 64, w_hh + (size_t)6 * 256 * 64,
                                       b_ih + (size_t)6 * 256, b_hh + (size_t)6 * 256,
                                       base, pw,
                                       &prod[6 * 64 + g], &cons[6 * 64 + g], nullptr, nullptr);
    }
}

// ---------------- output MLP: 64 -> 32 relu -> 4 ----------------
__global__ __launch_bounds__(256)
void mlp_out_kernel(const float* __restrict__ hin,
                    const float* __restrict__ wo1, const float* __restrict__ bo1,
                    const float* __restrict__ wo2, const float* __restrict__ bo2,
                    float* __restrict__ out) {
    __shared__ __align__(16) float wo1_s[32 * 64];
    __shared__ float bo1_s[32];
    __shared__ float wo2_s[4 * 32];
    __shared__ float bo2_s[4];
    const int tid = threadIdx.x;
    for (int e = tid; e < 32 * 64; e += 256) wo1_s[e] = wo1[e];
    if (tid < 32) bo1_s[tid] = bo1[tid];
    if (tid < 128) wo2_s[tid] = wo2[tid];
    if (tid < 4) bo2_s[tid] = bo2[tid];
    __syncthreads();

    const int gid = blockIdx.x * 256 + tid;
    const float4* hv = (const float4*)(hin + gid * 64);
    float4 h[16];
#pragma unroll
    for (int q = 0; q < 16; ++q) h[q] = hv[q];

    float m1[32];
#pragma unroll
    for (int o = 0; o < 32; ++o) {
        float acc = bo1_s[o];
        const float4* wrow = (const float4*)(wo1_s + o * 64);
#pragma unroll
        for (int q = 0; q < 16; ++q) {
            const float4 w = wrow[q];
            acc = fmaf(h[q].x, w.x, acc);
            acc = fmaf(h[q].y, w.y, acc);
            acc = fmaf(h[q].z, w.z, acc);
            acc = fmaf(h[q].w, w.w, acc);
        }
        m1[o] = fmaxf(0.f, acc);
    }
    float r[4];
#pragma unroll
    for (int q = 0; q < 4; ++q) {
        float acc = bo2_s[q];
#pragma unroll
        for (int o = 0; o < 32; ++o) acc = fmaf(m1[o], wo2_s[q * 32 + o], acc);
        r[q] = acc;
    }
    float4 res;
    res.x = r[0]; res.y = r[1]; res.z = r[2]; res.w = r[3];
    ((float4*)out)[gid] = res;
}

extern "C" void kernel_launch(void* const* d_in, const int* in_sizes, int n_in,
                              void* d_out, int out_size, void* d_ws, size_t ws_size,
                              hipStream_t stream) {
    const float* x     = (const float*)d_in[0];
    const float* w1    = (const float*)d_in[1];
    const float* b1    = (const float*)d_in[2];
    const float* w2    = (const float*)d_in[3];
    const float* b2    = (const float*)d_in[4];
    const float* w_ih0 = (const float*)d_in[5];
    const float* w_hh0 = (const float*)d_in[6];
    const float* b_ih0 = (const float*)d_in[7];
    const float* b_hh0 = (const float*)d_in[8];
    const float* w_ih  = (const float*)d_in[9];
    const float* w_hh  = (const float*)d_in[10];
    const float* b_ih  = (const float*)d_in[11];
    const float* b_hh  = (const float*)d_in[12];
    const float* wo1   = (const float*)d_in[13];
    const float* bo1   = (const float*)d_in[14];
    const float* wo2   = (const float*)d_in[15];
    const float* bo2   = (const float*)d_in[16];

    // ws layout (words): buf_mlp 2048*64*16 u32 | rings 7*2048*8*64 u32 |
    //                    finalb 2048*64*64 f32 | flags 2*7*64 int  (~71.5 MB)
    u32* buf_mlp = (u32*)d_ws;
    u32* rings   = buf_mlp + (size_t)BATCH * TT * 16;
    float* finalb = (float*)(rings + (size_t)7 * BATCH * RD * 64);
    int* flags   = (int*)(finalb + (size_t)BATCH * TT * 64);
    int* prod    = flags;            // 7*64
    int* cons    = flags + 7 * 64;   // 7*64

    const int nbt_blocks = (BATCH * TT) / 256;  // 512

    clear_flags_kernel<<<1, 256, 0, stream>>>(flags, 2 * 7 * 64);
    mlp_in_kernel<<<nbt_blocks, 256, 0, stream>>>(x, w1, b1, w2, b2, buf_mlp);
    lstm_pipe<<<512, 256, 0, stream>>>(buf_mlp, w_ih0, w_hh0, b_ih0, b_hh0,
                                       w_ih, w_hh, b_ih, b_hh,
                                       rings, finalb, prod, cons);
    mlp_out_kernel<<<nbt_blocks, 256, 0, stream>>>(finalb, wo1, bo1, wo2, bo2, (float*)d_out);
}

// Round 8
// 609.817 us; speedup vs baseline: 9.3004x; 9.3004x over previous
//
#include <hip/hip_runtime.h>

// x[2048,64,2] -> MLP(2->16 relu ->16) -> 8x LSTM(H=64) -> MLP(64->32 relu ->4)
// fp32 in/out. LSTM via split-bf16 MFMA (3-term, ~fp32 accuracy).
//
// Round 8: round 7's wave-specialized kernel with the phase-C row bug fixed:
//   D rows span 0..15 (row = quad*4+r) but blocks own M=8 rows -> only quads
//   0-1 hold real rows; quads 2-3 were writing phantom rows into neighboring
//   blocks' hbuf rows (the 2.4e-2 absmax). Phase C now guarded by quad<2.

#define BATCH 2048
#define TT 64
#define LDPW 68   // panel row stride in u32: 272B rows -> 16B-aligned, 2-way-free banks

typedef unsigned int u32;
typedef u32 u32x4 __attribute__((ext_vector_type(4)));
typedef short bf16x8 __attribute__((ext_vector_type(8)));
typedef float f32x4 __attribute__((ext_vector_type(4)));

__device__ __forceinline__ float sigmoid_fast(float x) {
    return __builtin_amdgcn_rcpf(1.f + __expf(-x));
}
__device__ __forceinline__ float tanh_fast(float x) {
    float e = __expf(-2.f * x);
    e = fminf(e, 1e30f);
    return (1.f - e) * __builtin_amdgcn_rcpf(1.f + e);
}
// fp32 -> (bf16 hi) | (bf16 lo of exact residual) << 16
__device__ __forceinline__ u32 pack_split(float x) {
    const u32 u = __float_as_uint(x);
    const float r = x - __uint_as_float(u & 0xFFFF0000u);
    return (u >> 16) | (__float_as_uint(r) & 0xFFFF0000u);
}
__device__ __forceinline__ void split2(float x, unsigned short& hi, unsigned short& lo) {
    const u32 u = __float_as_uint(x);
    hi = (unsigned short)(u >> 16);
    const float r = x - __uint_as_float(u & 0xFFFF0000u);
    lo = (unsigned short)(__float_as_uint(r) >> 16);
}
// 8 packed u32 -> hi-frag, lo-frag (bf16x8 each) via v_perm
__device__ __forceinline__ void unpack_frag(const u32x4 a, const u32x4 b, bf16x8& hi, bf16x8& lo) {
    union { bf16x8 v; u32 w[4]; } H, L;
    H.w[0] = __builtin_amdgcn_perm(a.y, a.x, 0x05040100u);
    H.w[1] = __builtin_amdgcn_perm(a.w, a.z, 0x05040100u);
    H.w[2] = __builtin_amdgcn_perm(b.y, b.x, 0x05040100u);
    H.w[3] = __builtin_amdgcn_perm(b.w, b.z, 0x05040100u);
    L.w[0] = __builtin_amdgcn_perm(a.y, a.x, 0x07060302u);
    L.w[1] = __builtin_amdgcn_perm(a.w, a.z, 0x07060302u);
    L.w[2] = __builtin_amdgcn_perm(b.y, b.x, 0x07060302u);
    L.w[3] = __builtin_amdgcn_perm(b.w, b.z, 0x07060302u);
    hi = H.v; lo = L.v;
}
__device__ __forceinline__ f32x4 mfma_bf16(bf16x8 a, bf16x8 b, f32x4 c) {
    return __builtin_amdgcn_mfma_f32_16x16x32_bf16(a, b, c, 0, 0, 0);
}

// ---------------- input MLP: 2 -> 16 relu -> 16 (packed hi/lo out) ----------------
__global__ __launch_bounds__(256)
void mlp_in_kernel(const float* __restrict__ x,
                   const float* __restrict__ w1, const float* __restrict__ b1,
                   const float* __restrict__ w2, const float* __restrict__ b2,
                   u32* __restrict__ out) {
    const int gid = blockIdx.x * 256 + threadIdx.x;
    const float x0 = x[gid * 2 + 0];
    const float x1 = x[gid * 2 + 1];
    float hid[16];
#pragma unroll
    for (int j = 0; j < 16; ++j) {
        float v = fmaf(x1, w1[j * 2 + 1], fmaf(x0, w1[j * 2 + 0], b1[j]));
        hid[j] = fmaxf(0.f, v);
    }
    u32 o[16];
#pragma unroll
    for (int oo = 0; oo < 16; ++oo) {
        float acc = b2[oo];
#pragma unroll
        for (int j = 0; j < 16; ++j) acc = fmaf(hid[j], w2[oo * 16 + j], acc);
        o[oo] = pack_split(acc);
    }
    u32x4* op = (u32x4*)(out + (size_t)gid * 16);
#pragma unroll
    for (int q = 0; q < 4; ++q) {
        u32x4 v = {o[q * 4 + 0], o[q * 4 + 1], o[q * 4 + 2], o[q * 4 + 3]};
        op[q] = v;
    }
}

// ---------------- wave-specialized LSTM layer ----------------
// IKT = # of 32-wide k-tiles for the x-part (1 for I=16, 2 for I=64).
template <int IKT, int I>
__global__ __launch_bounds__(512, 1)
void lstm_ws(const u32* __restrict__ xin,          // packed [row][TT][I]
             const float* __restrict__ w_ih, const float* __restrict__ w_hh,
             const float* __restrict__ b_ih, const float* __restrict__ b_hh,
             u32* __restrict__ hbuf) {              // packed [row][TT][64]
    __shared__ __align__(16) u32 panel[2][16 * LDPW];  // h state, rows 8..15 stay 0
    __shared__ __align__(16) float xg[2][4096];        // frag-dump [w][g][lane][4]

    const int tid = threadIdx.x;
    const int wv = tid >> 6, lane = tid & 63, l16 = lane & 15, quad = lane >> 4;
    const int base = blockIdx.x * 8;

    for (int e = tid; e < 2 * 16 * LDPW; e += 512) ((u32*)panel)[e] = 0;

    if (wv < 4) {
        // ---------------- consumer: recurrence + phase C ----------------
        bf16x8 bh[2][4], bl[2][4];   // W_hh B-frags: n = g*64 + wv*16 + l16
#pragma unroll
        for (int g = 0; g < 4; ++g) {
            const int n = g * 64 + wv * 16 + l16;
#pragma unroll
            for (int kt = 0; kt < 2; ++kt)
#pragma unroll
                for (int jj = 0; jj < 8; ++jj) {
                    const int k = kt * 32 + quad * 8 + jj;
                    unsigned short h_, l_;
                    split2(w_hh[n * 64 + k], h_, l_);
                    bh[kt][g][jj] = (short)h_;
                    bl[kt][g][jj] = (short)l_;
                }
        }
        float c[4] = {0.f, 0.f, 0.f, 0.f};   // quads 0-1: slot r -> (m = quad*4+r, j)
        const int j = wv * 16 + l16;
        const int xgo = (wv * 4 * 64 + lane) * 4;
        __syncthreads();

        for (int t = 0; t < TT; ++t) {
            const int p = t & 1;
            f32x4 acc[4];
#pragma unroll
            for (int g = 0; g < 4; ++g)
                acc[g] = *(const f32x4*)&xg[p][xgo + g * 256];
#pragma unroll
            for (int kt = 0; kt < 2; ++kt) {
                const int off = l16 * LDPW + kt * 32 + quad * 8;
                const u32x4 a = *(const u32x4*)&panel[p][off];
                const u32x4 b = *(const u32x4*)&panel[p][off + 4];
                bf16x8 fh, fl;
                unpack_frag(a, b, fh, fl);
#pragma unroll
                for (int g = 0; g < 4; ++g) {
                    acc[g] = mfma_bf16(fh, bh[kt][g], acc[g]);
                    acc[g] = mfma_bf16(fl, bh[kt][g], acc[g]);
                    acc[g] = mfma_bf16(fh, bl[kt][g], acc[g]);
                }
            }
            // phase C: reg-local. D row = quad*4+r spans 0..15 but only rows
            // 0..7 are real (M=8) -> quads 0-1 only. (Bug fixed vs round 7.)
            u32* pn = panel[p ^ 1];
            if (quad < 2) {
#pragma unroll
                for (int r = 0; r < 4; ++r) {
                    const int m = quad * 4 + r;
                    const float iv = sigmoid_fast(acc[0][r]);
                    const float fv = sigmoid_fast(acc[1][r]);
                    const float gv = tanh_fast(acc[2][r]);
                    const float ov = sigmoid_fast(acc[3][r]);
                    c[r] = fv * c[r] + iv * gv;
                    const float h = ov * tanh_fast(c[r]);
                    const u32 pk = pack_split(h);
                    pn[m * LDPW + j] = pk;
                    hbuf[((size_t)(base + m) * TT + t) * 64 + j] = pk;
                }
            }
            __syncthreads();
        }
    } else {
        // ---------------- producer: xg[t+1] = x[t+1] @ W_ih + bias ----------------
        const int w4 = wv - 4;
        bf16x8 ih[IKT][4], il[IKT][4];
        float bias[4];
#pragma unroll
        for (int g = 0; g < 4; ++g) {
            const int n = g * 64 + w4 * 16 + l16;
            bias[g] = b_ih[n] + b_hh[n];
#pragma unroll
            for (int kt = 0; kt < IKT; ++kt)
#pragma unroll
                for (int jj = 0; jj < 8; ++jj) {
                    const int k = kt * 32 + quad * 8 + jj;
                    const float w = (k < I) ? w_ih[n * I + k] : 0.f;
                    unsigned short h_, l_;
                    split2(w, h_, l_);
                    ih[kt][g][jj] = (short)h_;
                    il[kt][g][jj] = (short)l_;
                }
        }
        const int xgo = (w4 * 4 * 64 + lane) * 4;
        u32x4 xa[IKT], xb[IKT];
        const bool ld = (l16 < 8);

        auto load_x = [&](int ts) {
#pragma unroll
            for (int kt = 0; kt < IKT; ++kt) {
                u32x4 za = {0, 0, 0, 0}, zb = {0, 0, 0, 0};
                const int k0 = kt * 32 + quad * 8;
                if (ld && k0 < I) {
                    const u32* row = xin + ((size_t)(base + l16) * TT + ts) * I;
                    za = *(const u32x4*)&row[k0];
                    zb = *(const u32x4*)&row[k0 + 4];
                }
                xa[kt] = za; xb[kt] = zb;
            }
        };
        auto comp_xg = [&](int dst) {
            f32x4 acc[4];
#pragma unroll
            for (int g = 0; g < 4; ++g) {
                acc[g][0] = bias[g]; acc[g][1] = bias[g];
                acc[g][2] = bias[g]; acc[g][3] = bias[g];
            }
#pragma unroll
            for (int kt = 0; kt < IKT; ++kt) {
                bf16x8 fh, fl;
                unpack_frag(xa[kt], xb[kt], fh, fl);
#pragma unroll
                for (int g = 0; g < 4; ++g) {
                    acc[g] = mfma_bf16(fh, ih[kt][g], acc[g]);
                    acc[g] = mfma_bf16(fl, ih[kt][g], acc[g]);
                    acc[g] = mfma_bf16(fh, il[kt][g], acc[g]);
                }
            }
#pragma unroll
            for (int g = 0; g < 4; ++g)
                *(f32x4*)&xg[dst][xgo + g * 256] = acc[g];
        };

        load_x(0);
        comp_xg(0);            // xg for t=0
        load_x(1);             // x[1] into regs
        __syncthreads();

        for (int t = 0; t < TT; ++t) {
            const int p = t & 1;
            comp_xg(p ^ 1);                 // xg for t+1 (last iter: unused)
            load_x((t + 2) & (TT - 1));     // wrapped read: valid memory, unused result
            __syncthreads();
        }
    }
}

// ---------------- output MLP: 64 -> 32 relu -> 4 (packed input) ----------------
__global__ __launch_bounds__(256)
void mlp_out_kernel(const u32* __restrict__ hin,
                    const float* __restrict__ wo1, const float* __restrict__ bo1,
                    const float* __restrict__ wo2, const float* __restrict__ bo2,
                    float* __restrict__ out) {
    __shared__ __align__(16) float wo1_s[32 * 64];
    __shared__ float bo1_s[32];
    __shared__ float wo2_s[4 * 32];
    __shared__ float bo2_s[4];
    const int tid = threadIdx.x;
    for (int e = tid; e < 32 * 64; e += 256) wo1_s[e] = wo1[e];
    if (tid < 32) bo1_s[tid] = bo1[tid];
    if (tid < 128) wo2_s[tid] = wo2[tid];
    if (tid < 4) bo2_s[tid] = bo2[tid];
    __syncthreads();

    const int gid = blockIdx.x * 256 + tid;
    const u32x4* hv = (const u32x4*)(hin + (size_t)gid * 64);
    float h[64];
#pragma unroll
    for (int q = 0; q < 16; ++q) {
        const u32x4 v = hv[q];
#pragma unroll
        for (int e = 0; e < 4; ++e) {
            const u32 pk = v[e];
            h[q * 4 + e] = __uint_as_float(pk << 16) + __uint_as_float(pk & 0xFFFF0000u);
        }
    }

    float m1[32];
#pragma unroll
    for (int o = 0; o < 32; ++o) {
        float acc = bo1_s[o];
        const float* wrow = wo1_s + o * 64;
#pragma unroll
        for (int q = 0; q < 64; ++q) acc = fmaf(h[q], wrow[q], acc);
        m1[o] = fmaxf(0.f, acc);
    }
    float r[4];
#pragma unroll
    for (int q = 0; q < 4; ++q) {
        float acc = bo2_s[q];
#pragma unroll
        for (int o = 0; o < 32; ++o) acc = fmaf(m1[o], wo2_s[q * 32 + o], acc);
        r[q] = acc;
    }
    float4 res;
    res.x = r[0]; res.y = r[1]; res.z = r[2]; res.w = r[3];
    ((float4*)out)[gid] = res;
}

extern "C" void kernel_launch(void* const* d_in, const int* in_sizes, int n_in,
                              void* d_out, int out_size, void* d_ws, size_t ws_size,
                              hipStream_t stream) {
    const float* x     = (const float*)d_in[0];
    const float* w1    = (const float*)d_in[1];
    const float* b1    = (const float*)d_in[2];
    const float* w2    = (const float*)d_in[3];
    const float* b2    = (const float*)d_in[4];
    const float* w_ih0 = (const float*)d_in[5];
    const float* w_hh0 = (const float*)d_in[6];
    const float* b_ih0 = (const float*)d_in[7];
    const float* b_hh0 = (const float*)d_in[8];
    const float* w_ih  = (const float*)d_in[9];
    const float* w_hh  = (const float*)d_in[10];
    const float* b_ih  = (const float*)d_in[11];
    const float* b_hh  = (const float*)d_in[12];
    const float* wo1   = (const float*)d_in[13];
    const float* bo1   = (const float*)d_in[14];
    const float* wo2   = (const float*)d_in[15];
    const float* bo2   = (const float*)d_in[16];

    // ws: buf_mlp packed [B,T,16] u32 (8.4 MB) | hbuf packed [B,T,64] u32 (33.5 MB)
    u32* buf_mlp = (u32*)d_ws;
    u32* hbuf    = buf_mlp + (size_t)BATCH * TT * 16;

    const int nbt_blocks = (BATCH * TT) / 256;  // 512

    mlp_in_kernel<<<nbt_blocks, 256, 0, stream>>>(x, w1, b1, w2, b2, buf_mlp);

    lstm_ws<1, 16><<<BATCH / 8, 512, 0, stream>>>(buf_mlp, w_ih0, w_hh0, b_ih0, b_hh0, hbuf);
    for (int l = 0; l < 7; ++l) {
        lstm_ws<2, 64><<<BATCH / 8, 512, 0, stream>>>(
            hbuf, w_ih + (size_t)l * 256 * 64, w_hh + (size_t)l * 256 * 64,
            b_ih + (size_t)l * 256, b_hh + (size_t)l * 256, hbuf);
    }

    mlp_out_kernel<<<nbt_blocks, 256, 0, stream>>>(hbuf, wo1, bo1, wo2, bo2, (float*)d_out);
}